// Round 1
// baseline (609.017 us; speedup 1.0000x reference)
//
#include <hip/hip_runtime.h>

// Implicit-GEMM conv2d via bf16 MFMA.
// GEMM: M = Cout = 256, N = B*OH*OW = 123008, K = 9*128 = 1152 (k = tap*128 + ci)
// Block tile 128x128, BK=32, 4 waves (2x2), each wave 64x64 via 16 mfma_16x16x32_bf16.

using bf16x8 = __attribute__((ext_vector_type(8))) __bf16;
using f32x4  = __attribute__((ext_vector_type(4))) float;

constexpr int CIN  = 128;
constexpr int HW   = 64;     // input H = W = 64
constexpr int COUT = 256;
constexpr int OW   = 62;
constexpr int NS   = 62 * 62;          // 3844 spatial per batch
constexpr int NTOT = 32 * NS;          // 123008
constexpr int KTOT = 9 * CIN;          // 1152
constexpr int BM = 128, BN = 128, BK = 32;
constexpr int KSTEPS = KTOT / BK;      // 36

__device__ __forceinline__ unsigned short f2bf(float f) {
  unsigned u = __float_as_uint(f);
  u += 0x7fffu + ((u >> 16) & 1u);     // RNE
  return (unsigned short)(u >> 16);
}
__device__ __forceinline__ unsigned pack2(float a, float b) {
  return (unsigned)f2bf(a) | ((unsigned)f2bf(b) << 16);
}

__global__ __launch_bounds__(256)
void conv_mfma_kernel(const float* __restrict__ x, const float* __restrict__ w,
                      float* __restrict__ out) {
  // LDS tiles: [row][BK] bf16, row stride 32 elems (64B). 16B slot index g
  // swizzled by g^((row>>1)&3) -> conflict-free b128 reads/writes.
  __shared__ __align__(16) unsigned short As[BM * BK];
  __shared__ __align__(16) unsigned short Bs[BN * BK];

  const int t    = threadIdx.x;
  const int lane = t & 63;
  const int wid  = t >> 6;
  const int wm   = wid >> 1;           // wave row  (0..1)
  const int wn   = wid & 1;            // wave col  (0..1)

  const int co_base = blockIdx.x * BM; // 0 or 128
  const int n_base  = blockIdx.y * BN;

  // ---- B staging precompute: thread owns LDS row bn, 16B groups {bg0, bg0+2}
  const int bn  = t & 127;
  const int bg0 = t >> 7;
  {
  }
  const unsigned n0   = n_base + bn;       // always < NTOT (961*128 exact)
  const unsigned bidx = n0 / NS;
  const unsigned s0   = n0 - bidx * NS;
  const unsigned oh   = s0 / OW;
  const unsigned ow   = s0 - oh * OW;
  const float* xb = x + (bidx * (CIN * HW * HW) + oh * HW + ow);

  // ---- A staging precompute: thread owns LDS row am, groups {ag0, ag0+1}
  const int am  = t & 127;
  const int ag0 = (t >> 7) * 2;
  const float* wb = w + (co_base + am) * KTOT;   // + ci*9 + tap

  f32x4 acc[4][4] = {};

  for (int ks = 0; ks < KSTEPS; ++ks) {
    const int tap = ks >> 2;                 // 0..8, wave-uniform
    const int ci0 = (ks & 3) * BK;           // 0,32,64,96
    const int kh  = tap / 3;
    const int kw  = tap - kh * 3;
    const int xoff = kh * HW + kw;

    // ---- global loads to registers (f32)
    float av[2][8], bv[2][8];
#pragma unroll
    for (int gi = 0; gi < 2; ++gi) {
      const int g = ag0 + gi;
#pragma unroll
      for (int j = 0; j < 8; ++j)
        av[gi][j] = wb[(ci0 + g * 8 + j) * 9 + tap];     // stride-9, L2-resident
    }
#pragma unroll
    for (int gi = 0; gi < 2; ++gi) {
      const int g = bg0 + gi * 2;
#pragma unroll
      for (int j = 0; j < 8; ++j)
        bv[gi][j] = xb[xoff + (ci0 + g * 8 + j) * (HW * HW)]; // lanes coalesce over n
    }

    __syncthreads();   // previous iteration's LDS reads done

    // ---- convert + pack + swizzled ds_write_b128
#pragma unroll
    for (int gi = 0; gi < 2; ++gi) {
      const int g = ag0 + gi;
      uint4 pv;
      pv.x = pack2(av[gi][0], av[gi][1]);
      pv.y = pack2(av[gi][2], av[gi][3]);
      pv.z = pack2(av[gi][4], av[gi][5]);
      pv.w = pack2(av[gi][6], av[gi][7]);
      *reinterpret_cast<uint4*>(&As[am * 32 + ((g ^ ((am >> 1) & 3)) << 3)]) = pv;
    }
#pragma unroll
    for (int gi = 0; gi < 2; ++gi) {
      const int g = bg0 + gi * 2;
      uint4 pv;
      pv.x = pack2(bv[gi][0], bv[gi][1]);
      pv.y = pack2(bv[gi][2], bv[gi][3]);
      pv.z = pack2(bv[gi][4], bv[gi][5]);
      pv.w = pack2(bv[gi][6], bv[gi][7]);
      *reinterpret_cast<uint4*>(&Bs[bn * 32 + ((g ^ ((bn >> 1) & 3)) << 3)]) = pv;
    }

    __syncthreads();   // tile ready

    // ---- fragment reads (swizzled b128) + 16 MFMAs
    bf16x8 af[4], bfr[4];
    const int g = lane >> 4;
#pragma unroll
    for (int mi = 0; mi < 4; ++mi) {
      const int m = wm * 64 + mi * 16 + (lane & 15);
      af[mi] = *reinterpret_cast<const bf16x8*>(&As[m * 32 + ((g ^ ((m >> 1) & 3)) << 3)]);
    }
#pragma unroll
    for (int ni = 0; ni < 4; ++ni) {
      const int nn = wn * 64 + ni * 16 + (lane & 15);
      bfr[ni] = *reinterpret_cast<const bf16x8*>(&Bs[nn * 32 + ((g ^ ((nn >> 1) & 3)) << 3)]);
    }
#pragma unroll
    for (int mi = 0; mi < 4; ++mi)
#pragma unroll
      for (int ni = 0; ni < 4; ++ni)
        acc[mi][ni] = __builtin_amdgcn_mfma_f32_16x16x32_bf16(af[mi], bfr[ni],
                                                              acc[mi][ni], 0, 0, 0);
  }

  // ---- epilogue: D col = lane&15 (n), row = (lane>>4)*4 + r (co)
#pragma unroll
  for (int ni = 0; ni < 4; ++ni) {
    const unsigned n  = n_base + wn * 64 + ni * 16 + (lane & 15);
    const unsigned b2 = n / NS;
    const unsigned s2 = n - b2 * NS;
    float* op = out + (size_t)b2 * (COUT * NS) + s2
                    + (size_t)(co_base + wm * 64 + (lane >> 4) * 4) * NS;
#pragma unroll
    for (int mi = 0; mi < 4; ++mi)
#pragma unroll
      for (int r = 0; r < 4; ++r)
        op[(mi * 16 + r) * NS] = acc[mi][ni][r];
  }
}

extern "C" void kernel_launch(void* const* d_in, const int* in_sizes, int n_in,
                              void* d_out, int out_size, void* d_ws, size_t ws_size,
                              hipStream_t stream) {
  const float* x = (const float*)d_in[0];   // [32,128,64,64]
  const float* w = (const float*)d_in[1];   // [256,128,3,3]
  float* out = (float*)d_out;               // [32,256,62,62]
  dim3 grid(COUT / BM, NTOT / BN);          // (2, 961)
  conv_mfma_kernel<<<grid, 256, 0, stream>>>(x, w, out);
}

// Round 2
// 141.932 us; speedup vs baseline: 4.2909x; 4.2909x over previous
//
#include <hip/hip_runtime.h>

// Implicit-GEMM conv2d via bf16 MFMA, with ws-staged pre-pack:
//   A' [256][1152] bf16, k = tap*128+ci   (from w [256][128][3][3] f32)
//   xp [32][64][64][128] bf16 (NHWC)       (from x [32][128][64][64] f32)
// Main: M=256, N=123008, K=1152; 128x128 tile, BK=32, 4 waves (2x2),
// global_load_lds width-16 staging with source-side swizzle (LDS linear).

using bf16x8 = __attribute__((ext_vector_type(8))) __bf16;
using f32x4  = __attribute__((ext_vector_type(4))) float;

constexpr int CIN  = 128;
constexpr int HW   = 64;
constexpr int COUT = 256;
constexpr int OW   = 62;
constexpr int NS   = 62 * 62;          // 3844
constexpr int NTOT = 32 * NS;          // 123008
constexpr int KTOT = 9 * CIN;          // 1152
constexpr int BM = 128, BN = 128, BK = 32;
constexpr int KSTEPS = KTOT / BK;      // 36

constexpr size_t AP_BYTES = (size_t)COUT * KTOT * 2;            // 589824
constexpr size_t XP_BYTES = (size_t)32 * HW * HW * CIN * 2;     // 33554432
constexpr size_t WS_NEEDED = AP_BYTES + XP_BYTES;

__device__ __forceinline__ unsigned short f2bf(float f) {
  unsigned u = __float_as_uint(f);
  u += 0x7fffu + ((u >> 16) & 1u);     // RNE
  return (unsigned short)(u >> 16);
}
__device__ __forceinline__ unsigned pack2(float a, float b) {
  return (unsigned)f2bf(a) | ((unsigned)f2bf(b) << 16);
}

__device__ __forceinline__ void gld16(const void* g, void* l) {
  __builtin_amdgcn_global_load_lds(
      (const __attribute__((address_space(1))) unsigned int*)g,
      (__attribute__((address_space(3))) unsigned int*)l, 16, 0, 0);
}

// ---------------- prepack kernels ----------------

__global__ __launch_bounds__(256)
void prepack_w(const float* __restrict__ w, unsigned* __restrict__ ap32) {
  const int idx = blockIdx.x * 256 + threadIdx.x;     // 0..147455
  const int co  = idx / 576;
  const int k2  = idx - co * 576;
  const int k   = k2 * 2;
  const int tap = k >> 7;
  const int ci  = k & 127;
  const float v0 = w[(co * 128 + ci) * 9 + tap];
  const float v1 = w[(co * 128 + ci + 1) * 9 + tap];
  ap32[idx] = pack2(v0, v1);
}

__global__ __launch_bounds__(256)
void prepack_x(const float* __restrict__ x, unsigned* __restrict__ xp32) {
  const int bh = blockIdx.x;           // b*64 + h
  const int b  = bh >> 6, h = bh & 63;
  const int t  = threadIdx.x;
  const int c  = t & 63;               // ci-pair index (ci = 2c, 2c+1)
  const int w0 = (t >> 6) * 16;

  const float* p0 = x + (((size_t)(b * 128 + 2 * c) * HW) + h) * HW + w0;
  const float* p1 = p0 + (size_t)HW * HW;
  float r0[16], r1[16];
#pragma unroll
  for (int j = 0; j < 4; ++j) {
    *reinterpret_cast<float4*>(&r0[j * 4]) = reinterpret_cast<const float4*>(p0)[j];
    *reinterpret_cast<float4*>(&r1[j * 4]) = reinterpret_cast<const float4*>(p1)[j];
  }
  unsigned* o = xp32 + ((size_t)bh * HW + w0) * 64 + c;
#pragma unroll
  for (int j = 0; j < 16; ++j)
    o[j * 64] = pack2(r0[j], r1[j]);
}

// ---------------- main kernel ----------------

__global__ __launch_bounds__(256)
void conv_main(const unsigned short* __restrict__ Ap,
               const unsigned short* __restrict__ Xp,
               float* __restrict__ out) {
  // LDS linear [row][32 bf16]; 16B slot g holds global slot g ^ ((row>>1)&3)
  __shared__ __align__(16) unsigned short As[BM * BK];
  __shared__ __align__(16) unsigned short Bs[BN * BK];

  const int t    = threadIdx.x;
  const int lane = t & 63;
  const int wid  = t >> 6;
  const int wm   = wid >> 1;
  const int wn   = wid & 1;
  const int co_base = blockIdx.x * BM;
  const int n_base  = blockIdx.y * BN;

  // staging: chunk = wid*2+q covers rows [chunk*16, +16); lane -> row chunk*16+(lane>>2), slot lane&3
  int aoff[2];        // ushort index into Ap, k-independent part
  unsigned xbase[2];  // ushort index into Xp, k-independent part
#pragma unroll
  for (int q = 0; q < 2; ++q) {
    const int r  = (wid * 2 + q) * 16 + (lane >> 2);
    const int sl = (lane & 3) ^ ((r >> 1) & 3);       // source-side swizzle
    aoff[q] = (co_base + r) * KTOT + sl * 8;
    const unsigned n  = n_base + r;
    const unsigned bi = n / NS;
    const unsigned s0 = n - bi * NS;
    const unsigned oh = s0 / OW;
    const unsigned ow = s0 - oh * OW;
    xbase[q] = (((bi * HW + oh) * HW) + ow) * CIN + sl * 8;
  }

  f32x4 acc[4][4] = {};

  for (int ks = 0; ks < KSTEPS; ++ks) {
    const int tap = ks >> 2;
    const int ci0 = (ks & 3) << 5;
    const int kh  = tap / 3;
    const int kw  = tap - kh * 3;
    const int akoff = tap * CIN + ci0;
    const int xkoff = (kh * HW + kw) * CIN + ci0;

#pragma unroll
    for (int q = 0; q < 2; ++q) {
      gld16(Ap + aoff[q] + akoff, (char*)As + (wid * 2 + q) * 1024);
      gld16(Xp + xbase[q] + xkoff, (char*)Bs + (wid * 2 + q) * 1024);
    }

    __syncthreads();   // drains vmcnt (loads -> LDS done) + barrier

    bf16x8 af[4], bfr[4];
    const int g  = lane >> 4;
    const int fr = lane & 15;
#pragma unroll
    for (int mi = 0; mi < 4; ++mi) {
      const int m = wm * 64 + mi * 16 + fr;
      af[mi] = *reinterpret_cast<const bf16x8*>(&As[m * 32 + ((g ^ ((m >> 1) & 3)) << 3)]);
    }
#pragma unroll
    for (int ni = 0; ni < 4; ++ni) {
      const int nn = wn * 64 + ni * 16 + fr;
      bfr[ni] = *reinterpret_cast<const bf16x8*>(&Bs[nn * 32 + ((g ^ ((nn >> 1) & 3)) << 3)]);
    }
#pragma unroll
    for (int mi = 0; mi < 4; ++mi)
#pragma unroll
      for (int ni = 0; ni < 4; ++ni)
        acc[mi][ni] = __builtin_amdgcn_mfma_f32_16x16x32_bf16(af[mi], bfr[ni],
                                                              acc[mi][ni], 0, 0, 0);

    __syncthreads();   // LDS reads done before next stage overwrites
  }

  // epilogue: D col = lane&15 (n), row = (lane>>4)*4 + r (co)
#pragma unroll
  for (int ni = 0; ni < 4; ++ni) {
    const unsigned n  = n_base + wn * 64 + ni * 16 + (lane & 15);
    const unsigned b2 = n / NS;
    const unsigned s2 = n - b2 * NS;
    float* op = out + (size_t)b2 * (COUT * NS) + s2
                    + (size_t)(co_base + wm * 64 + (lane >> 4) * 4) * NS;
#pragma unroll
    for (int mi = 0; mi < 4; ++mi)
#pragma unroll
      for (int r = 0; r < 4; ++r)
        op[(mi * 16 + r) * NS] = acc[mi][ni][r];
  }
}

// ---------------- fallback (round-1 kernel, used only if ws too small) ----------------

__global__ __launch_bounds__(256)
void conv_fallback(const float* __restrict__ x, const float* __restrict__ w,
                   float* __restrict__ out) {
  __shared__ __align__(16) unsigned short As[BM * BK];
  __shared__ __align__(16) unsigned short Bs[BN * BK];

  const int t    = threadIdx.x;
  const int lane = t & 63;
  const int wid  = t >> 6;
  const int wm   = wid >> 1;
  const int wn   = wid & 1;
  const int co_base = blockIdx.x * BM;
  const int n_base  = blockIdx.y * BN;

  const int bn  = t & 127;
  const int bg0 = t >> 7;
  const unsigned n0   = n_base + bn;
  const unsigned bidx = n0 / NS;
  const unsigned s0   = n0 - bidx * NS;
  const unsigned oh   = s0 / OW;
  const unsigned ow   = s0 - oh * OW;
  const float* xb = x + (bidx * (CIN * HW * HW) + oh * HW + ow);

  const int am  = t & 127;
  const int ag0 = (t >> 7) * 2;
  const float* wb = w + (co_base + am) * KTOT;

  f32x4 acc[4][4] = {};

  for (int ks = 0; ks < KSTEPS; ++ks) {
    const int tap = ks >> 2;
    const int ci0 = (ks & 3) * BK;
    const int kh  = tap / 3;
    const int kw  = tap - kh * 3;
    const int xoff = kh * HW + kw;

    float av[2][8], bv[2][8];
#pragma unroll
    for (int gi = 0; gi < 2; ++gi) {
      const int g = ag0 + gi;
#pragma unroll
      for (int j = 0; j < 8; ++j)
        av[gi][j] = wb[(ci0 + g * 8 + j) * 9 + tap];
    }
#pragma unroll
    for (int gi = 0; gi < 2; ++gi) {
      const int g = bg0 + gi * 2;
#pragma unroll
      for (int j = 0; j < 8; ++j)
        bv[gi][j] = xb[xoff + (ci0 + g * 8 + j) * (HW * HW)];
    }

    __syncthreads();

#pragma unroll
    for (int gi = 0; gi < 2; ++gi) {
      const int g = ag0 + gi;
      uint4 pv;
      pv.x = pack2(av[gi][0], av[gi][1]);
      pv.y = pack2(av[gi][2], av[gi][3]);
      pv.z = pack2(av[gi][4], av[gi][5]);
      pv.w = pack2(av[gi][6], av[gi][7]);
      *reinterpret_cast<uint4*>(&As[am * 32 + ((g ^ ((am >> 1) & 3)) << 3)]) = pv;
    }
#pragma unroll
    for (int gi = 0; gi < 2; ++gi) {
      const int g = bg0 + gi * 2;
      uint4 pv;
      pv.x = pack2(bv[gi][0], bv[gi][1]);
      pv.y = pack2(bv[gi][2], bv[gi][3]);
      pv.z = pack2(bv[gi][4], bv[gi][5]);
      pv.w = pack2(bv[gi][6], bv[gi][7]);
      *reinterpret_cast<uint4*>(&Bs[bn * 32 + ((g ^ ((bn >> 1) & 3)) << 3)]) = pv;
    }

    __syncthreads();

    bf16x8 af[4], bfr[4];
    const int g = lane >> 4;
#pragma unroll
    for (int mi = 0; mi < 4; ++mi) {
      const int m = wm * 64 + mi * 16 + (lane & 15);
      af[mi] = *reinterpret_cast<const bf16x8*>(&As[m * 32 + ((g ^ ((m >> 1) & 3)) << 3)]);
    }
#pragma unroll
    for (int ni = 0; ni < 4; ++ni) {
      const int nn = wn * 64 + ni * 16 + (lane & 15);
      bfr[ni] = *reinterpret_cast<const bf16x8*>(&Bs[nn * 32 + ((g ^ ((nn >> 1) & 3)) << 3)]);
    }
#pragma unroll
    for (int mi = 0; mi < 4; ++mi)
#pragma unroll
      for (int ni = 0; ni < 4; ++ni)
        acc[mi][ni] = __builtin_amdgcn_mfma_f32_16x16x32_bf16(af[mi], bfr[ni],
                                                              acc[mi][ni], 0, 0, 0);
  }

#pragma unroll
  for (int ni = 0; ni < 4; ++ni) {
    const unsigned n  = n_base + wn * 64 + ni * 16 + (lane & 15);
    const unsigned b2 = n / NS;
    const unsigned s2 = n - b2 * NS;
    float* op = out + (size_t)b2 * (COUT * NS) + s2
                    + (size_t)(co_base + wm * 64 + (lane >> 4) * 4) * NS;
#pragma unroll
    for (int mi = 0; mi < 4; ++mi)
#pragma unroll
      for (int r = 0; r < 4; ++r)
        op[(mi * 16 + r) * NS] = acc[mi][ni][r];
  }
}

extern "C" void kernel_launch(void* const* d_in, const int* in_sizes, int n_in,
                              void* d_out, int out_size, void* d_ws, size_t ws_size,
                              hipStream_t stream) {
  const float* x = (const float*)d_in[0];   // [32,128,64,64]
  const float* w = (const float*)d_in[1];   // [256,128,3,3]
  float* out = (float*)d_out;               // [32,256,62,62]
  dim3 grid(COUT / BM, NTOT / BN);          // (2, 961)

  if (ws_size >= WS_NEEDED) {
    unsigned* ap32 = (unsigned*)d_ws;
    unsigned short* Ap = (unsigned short*)d_ws;
    unsigned short* Xp = (unsigned short*)((char*)d_ws + AP_BYTES);
    unsigned* xp32 = (unsigned*)Xp;
    prepack_w<<<576, 256, 0, stream>>>(w, ap32);
    prepack_x<<<32 * HW, 256, 0, stream>>>(x, xp32);
    conv_main<<<grid, 256, 0, stream>>>(Ap, Xp, out);
  } else {
    conv_fallback<<<grid, 256, 0, stream>>>(x, w, out);
  }
}

// Round 3
// 113.483 us; speedup vs baseline: 5.3666x; 1.2507x over previous
//
#include <hip/hip_runtime.h>

// Implicit-GEMM conv2d via bf16 MFMA, ws-staged pre-pack + triple-buffered
// counted-vmcnt pipelined main loop.
//   A' [256][1152] bf16, k = tap*128+ci   (from w [256][128][3][3] f32)
//   xp [32][64][64][128] bf16 (NHWC)       (from x [32][128][64][64] f32)
// GEMM: M=256=Cout, N=123008, K=1152. Block tile 256x128, BK=64, 512 thr,
// 8 waves (4Mx2N), wave tile 64x64. LDS 3 x (A 32KB + B 16KB) = 144KB.
// One raw s_barrier per K-tile; s_waitcnt vmcnt(6) counted (depth-2 prefetch).

using bf16x8 = __attribute__((ext_vector_type(8))) __bf16;
using f32x4  = __attribute__((ext_vector_type(4))) float;

constexpr int CIN  = 128;
constexpr int HW   = 64;
constexpr int COUT = 256;
constexpr int OW   = 62;
constexpr int NS   = 62 * 62;          // 3844
constexpr int NTOT = 32 * NS;          // 123008
constexpr int KTOT = 9 * CIN;          // 1152
constexpr int BM = 256, BN = 128, BK = 64;
constexpr int NT = KTOT / BK;          // 18 K-tiles

constexpr size_t AP_BYTES = (size_t)COUT * KTOT * 2;            // 589824
constexpr size_t XP_BYTES = (size_t)32 * HW * HW * CIN * 2;     // 33554432
constexpr size_t WS_NEEDED = AP_BYTES + XP_BYTES;

constexpr int BUF_BYTES = 49152;       // per pipeline stage: A 32KB + B 16KB
constexpr int BOFF_B    = 32768;       // B offset inside a stage buffer

__device__ __forceinline__ unsigned short f2bf(float f) {
  unsigned u = __float_as_uint(f);
  u += 0x7fffu + ((u >> 16) & 1u);     // RNE
  return (unsigned short)(u >> 16);
}
__device__ __forceinline__ unsigned pack2(float a, float b) {
  return (unsigned)f2bf(a) | ((unsigned)f2bf(b) << 16);
}

__device__ __forceinline__ void gld16(const void* g, void* l) {
  __builtin_amdgcn_global_load_lds(
      (const __attribute__((address_space(1))) unsigned int*)g,
      (__attribute__((address_space(3))) unsigned int*)l, 16, 0, 0);
}

// ---------------- prepack kernels ----------------

__global__ __launch_bounds__(256)
void prepack_w(const float* __restrict__ w, unsigned* __restrict__ ap32) {
  const int idx = blockIdx.x * 256 + threadIdx.x;     // 0..147455
  const int co  = idx / 576;
  const int k2  = idx - co * 576;
  const int k   = k2 * 2;
  const int tap = k >> 7;
  const int ci  = k & 127;
  const float v0 = w[(co * 128 + ci) * 9 + tap];
  const float v1 = w[(co * 128 + ci + 1) * 9 + tap];
  ap32[idx] = pack2(v0, v1);
}

__global__ __launch_bounds__(256)
void prepack_x(const float* __restrict__ x, unsigned* __restrict__ xp32) {
  const int bh = blockIdx.x;           // b*64 + h
  const int b  = bh >> 6, h = bh & 63;
  const int t  = threadIdx.x;
  const int c  = t & 63;               // ci-pair index (ci = 2c, 2c+1)
  const int w0 = (t >> 6) * 16;

  const float* p0 = x + (((size_t)(b * 128 + 2 * c) * HW) + h) * HW + w0;
  const float* p1 = p0 + (size_t)HW * HW;
  float r0[16], r1[16];
#pragma unroll
  for (int j = 0; j < 4; ++j) {
    *reinterpret_cast<float4*>(&r0[j * 4]) = reinterpret_cast<const float4*>(p0)[j];
    *reinterpret_cast<float4*>(&r1[j * 4]) = reinterpret_cast<const float4*>(p1)[j];
  }
  unsigned* o = xp32 + ((size_t)bh * HW + w0) * 64 + c;
#pragma unroll
  for (int j = 0; j < 16; ++j)
    o[j * 64] = pack2(r0[j], r1[j]);
}

// ---------------- main kernel ----------------

__global__ __launch_bounds__(512, 2)
void conv_main(const unsigned short* __restrict__ Ap,
               const unsigned short* __restrict__ Xp,
               float* __restrict__ out) {
  // LDS stage buffer layout: rows of 64 bf16 (128B = 8 x 16B slots); LDS slot s
  // of row r holds global k-slot g = s ^ (r&7). Staged linearly by
  // global_load_lds (1KB per wave-call = 8 rows), source pre-swizzled.
  __shared__ __align__(16) char lds[3 * BUF_BYTES];   // 144 KiB

  const int tid  = threadIdx.x;
  const int lane = tid & 63;
  const int wid  = tid >> 6;       // 0..7
  const int wm   = wid >> 1;       // 0..3 (M quadrant, 64 rows each)
  const int wn   = wid & 1;        // 0..1 (N half, 64 cols each)
  const int n_base = blockIdx.x * BN;

  // ---- staging source offsets (element units) ----
  const int l3  = lane >> 3;                 // 0..7 = row within 8-row chunk
  const int sw8 = ((lane & 7) ^ l3) * 8;     // pre-swizzled slot (elements)
  int aoff[4];
#pragma unroll
  for (int q = 0; q < 4; ++q) {
    const int r = (wid * 4 + q) * 8 + l3;    // co row 0..255
    aoff[q] = r * KTOT + sw8;
  }
  unsigned xoff[2];
#pragma unroll
  for (int q = 0; q < 2; ++q) {
    const int rn = (wid * 2 + q) * 8 + l3;   // n row within tile 0..127
    const unsigned n  = n_base + rn;
    const unsigned bi = n / NS;
    const unsigned s0 = n - bi * NS;
    const unsigned oh = s0 / OW;
    const unsigned ww = s0 - oh * OW;
    xoff[q] = ((bi * HW + oh) * HW + ww) * CIN + sw8;
  }

  // ---- fragment read address parts (byte offsets within a stage buffer) ----
  const int fr  = lane & 15;
  const int gl  = lane >> 4;       // 0..3
  const int f7  = fr & 7;
  const int sw0 = ((0 * 4 + gl) ^ f7) * 16;  // kk=0 slot byte offset
  const int sw1 = ((1 * 4 + gl) ^ f7) * 16;  // kk=1
  const int arow = (wm * 64 + fr) * 128;
  const int brow = BOFF_B + (wn * 64 + fr) * 128;

  f32x4 acc[4][4] = {};

  auto STAGE = [&](int t, int buf) {
    const int tap   = t >> 1;
    const int kh    = tap / 3;
    const int kw    = tap - kh * 3;
    const int akoff = t * 64;                          // k = tap*128 + ci0
    const int xkoff = (kh * HW + kw) * CIN + (t & 1) * 64;
    char* lb = lds + buf * BUF_BYTES;
#pragma unroll
    for (int q = 0; q < 4; ++q)
      gld16(Ap + aoff[q] + akoff, lb + (wid * 4 + q) * 1024);
#pragma unroll
    for (int q = 0; q < 2; ++q)
      gld16(Xp + xoff[q] + xkoff, lb + BOFF_B + (wid * 2 + q) * 1024);
  };

  STAGE(0, 0);     // 6 chunks/thread in flight
  STAGE(1, 1);     // 12 in flight

#pragma unroll
  for (int t = 0; t < NT; ++t) {
    const int cb = t % 3;                    // compile-time after unroll
    // wait for tile t's 6 chunks (oldest); tile t+1's 6 stay in flight
    if (t < NT - 1) asm volatile("s_waitcnt vmcnt(6)" ::: "memory");
    else            asm volatile("s_waitcnt vmcnt(0)" ::: "memory");
    __builtin_amdgcn_s_barrier();
    __builtin_amdgcn_sched_barrier(0);

    const char* lb = lds + cb * BUF_BYTES;

    bf16x8 a0[4], b0[4];
#pragma unroll
    for (int mi = 0; mi < 4; ++mi)
      a0[mi] = *reinterpret_cast<const bf16x8*>(lb + arow + mi * 2048 + sw0);
#pragma unroll
    for (int ni = 0; ni < 4; ++ni)
      b0[ni] = *reinterpret_cast<const bf16x8*>(lb + brow + ni * 2048 + sw0);

    if (t < NT - 2) STAGE(t + 2, (t + 2) % 3);   // issue next-next tile

    __builtin_amdgcn_s_setprio(1);
#pragma unroll
    for (int mi = 0; mi < 4; ++mi)
#pragma unroll
      for (int ni = 0; ni < 4; ++ni)
        acc[mi][ni] = __builtin_amdgcn_mfma_f32_16x16x32_bf16(a0[mi], b0[ni],
                                                              acc[mi][ni], 0, 0, 0);
    __builtin_amdgcn_s_setprio(0);

    bf16x8 a1[4], b1[4];
#pragma unroll
    for (int mi = 0; mi < 4; ++mi)
      a1[mi] = *reinterpret_cast<const bf16x8*>(lb + arow + mi * 2048 + sw1);
#pragma unroll
    for (int ni = 0; ni < 4; ++ni)
      b1[ni] = *reinterpret_cast<const bf16x8*>(lb + brow + ni * 2048 + sw1);

    __builtin_amdgcn_s_setprio(1);
#pragma unroll
    for (int mi = 0; mi < 4; ++mi)
#pragma unroll
      for (int ni = 0; ni < 4; ++ni)
        acc[mi][ni] = __builtin_amdgcn_mfma_f32_16x16x32_bf16(a1[mi], b1[ni],
                                                              acc[mi][ni], 0, 0, 0);
    __builtin_amdgcn_s_setprio(0);
  }

  // ---- epilogue: D col = lane&15 (n), row = (lane>>4)*4 + r (co) ----
#pragma unroll
  for (int ni = 0; ni < 4; ++ni) {
    const unsigned n  = n_base + wn * 64 + ni * 16 + (lane & 15);
    const unsigned b2 = n / NS;
    const unsigned s2 = n - b2 * NS;
    float* op = out + (size_t)b2 * (COUT * NS) + s2
                    + (size_t)(wm * 64 + (lane >> 4) * 4) * NS;
#pragma unroll
    for (int mi = 0; mi < 4; ++mi)
#pragma unroll
      for (int r = 0; r < 4; ++r)
        op[(mi * 16 + r) * NS] = acc[mi][ni][r];
  }
}

// ---------------- fallback (no-ws path, round-1 proven) ----------------

__global__ __launch_bounds__(256)
void conv_fallback(const float* __restrict__ x, const float* __restrict__ w,
                   float* __restrict__ out) {
  __shared__ __align__(16) unsigned short As[128 * 32];
  __shared__ __align__(16) unsigned short Bs[128 * 32];

  const int t    = threadIdx.x;
  const int lane = t & 63;
  const int wid  = t >> 6;
  const int wm   = wid >> 1;
  const int wn   = wid & 1;
  const int co_base = blockIdx.x * 128;
  const int n_base  = blockIdx.y * 128;

  const int bn  = t & 127;
  const int bg0 = t >> 7;
  const unsigned n0   = n_base + bn;
  const unsigned bidx = n0 / NS;
  const unsigned s0   = n0 - bidx * NS;
  const unsigned oh   = s0 / OW;
  const unsigned ow   = s0 - oh * OW;
  const float* xb = x + (bidx * (CIN * HW * HW) + oh * HW + ow);

  const int am  = t & 127;
  const int ag0 = (t >> 7) * 2;
  const float* wb = w + (co_base + am) * KTOT;

  f32x4 acc[4][4] = {};

  for (int ks = 0; ks < 36; ++ks) {
    const int tap = ks >> 2;
    const int ci0 = (ks & 3) * 32;
    const int kh  = tap / 3;
    const int kw  = tap - kh * 3;
    const int xo  = kh * HW + kw;

    float av[2][8], bv[2][8];
#pragma unroll
    for (int gi = 0; gi < 2; ++gi) {
      const int g = ag0 + gi;
#pragma unroll
      for (int j = 0; j < 8; ++j)
        av[gi][j] = wb[(ci0 + g * 8 + j) * 9 + tap];
    }
#pragma unroll
    for (int gi = 0; gi < 2; ++gi) {
      const int g = bg0 + gi * 2;
#pragma unroll
      for (int j = 0; j < 8; ++j)
        bv[gi][j] = xb[xo + (ci0 + g * 8 + j) * (HW * HW)];
    }

    __syncthreads();

#pragma unroll
    for (int gi = 0; gi < 2; ++gi) {
      const int g = ag0 + gi;
      uint4 pv;
      pv.x = pack2(av[gi][0], av[gi][1]);
      pv.y = pack2(av[gi][2], av[gi][3]);
      pv.z = pack2(av[gi][4], av[gi][5]);
      pv.w = pack2(av[gi][6], av[gi][7]);
      *reinterpret_cast<uint4*>(&As[am * 32 + ((g ^ ((am >> 1) & 3)) << 3)]) = pv;
    }
#pragma unroll
    for (int gi = 0; gi < 2; ++gi) {
      const int g = bg0 + gi * 2;
      uint4 pv;
      pv.x = pack2(bv[gi][0], bv[gi][1]);
      pv.y = pack2(bv[gi][2], bv[gi][3]);
      pv.z = pack2(bv[gi][4], bv[gi][5]);
      pv.w = pack2(bv[gi][6], bv[gi][7]);
      *reinterpret_cast<uint4*>(&Bs[bn * 32 + ((g ^ ((bn >> 1) & 3)) << 3)]) = pv;
    }

    __syncthreads();

    bf16x8 af[4], bfr[4];
    const int g = lane >> 4;
#pragma unroll
    for (int mi = 0; mi < 4; ++mi) {
      const int m = wm * 64 + mi * 16 + (lane & 15);
      af[mi] = *reinterpret_cast<const bf16x8*>(&As[m * 32 + ((g ^ ((m >> 1) & 3)) << 3)]);
    }
#pragma unroll
    for (int ni = 0; ni < 4; ++ni) {
      const int nn = wn * 64 + ni * 16 + (lane & 15);
      bfr[ni] = *reinterpret_cast<const bf16x8*>(&Bs[nn * 32 + ((g ^ ((nn >> 1) & 3)) << 3)]);
    }
#pragma unroll
    for (int mi = 0; mi < 4; ++mi)
#pragma unroll
      for (int ni = 0; ni < 4; ++ni)
        acc[mi][ni] = __builtin_amdgcn_mfma_f32_16x16x32_bf16(af[mi], bfr[ni],
                                                              acc[mi][ni], 0, 0, 0);
  }

#pragma unroll
  for (int ni = 0; ni < 4; ++ni) {
    const unsigned n  = n_base + wn * 64 + ni * 16 + (lane & 15);
    const unsigned b2 = n / NS;
    const unsigned s2 = n - b2 * NS;
    float* op = out + (size_t)b2 * (COUT * NS) + s2
                    + (size_t)(co_base + wm * 64 + (lane >> 4) * 4) * NS;
#pragma unroll
    for (int mi = 0; mi < 4; ++mi)
#pragma unroll
      for (int r = 0; r < 4; ++r)
        op[(mi * 16 + r) * NS] = acc[mi][ni][r];
  }
}

extern "C" void kernel_launch(void* const* d_in, const int* in_sizes, int n_in,
                              void* d_out, int out_size, void* d_ws, size_t ws_size,
                              hipStream_t stream) {
  const float* x = (const float*)d_in[0];   // [32,128,64,64]
  const float* w = (const float*)d_in[1];   // [256,128,3,3]
  float* out = (float*)d_out;               // [32,256,62,62]

  if (ws_size >= WS_NEEDED) {
    unsigned* ap32 = (unsigned*)d_ws;
    unsigned short* Ap = (unsigned short*)d_ws;
    unsigned short* Xp = (unsigned short*)((char*)d_ws + AP_BYTES);
    unsigned* xp32 = (unsigned*)Xp;
    prepack_w<<<576, 256, 0, stream>>>(w, ap32);
    prepack_x<<<32 * HW, 256, 0, stream>>>(x, xp32);
    conv_main<<<dim3(NTOT / BN), 512, 0, stream>>>(Ap, Xp, out);
  } else {
    conv_fallback<<<dim3(2, NTOT / 128), 256, 0, stream>>>(x, w, out);
  }
}